// Round 14
// baseline (301.177 us; speedup 1.0000x reference)
//
#include <hip/hip_runtime.h>

// x[16,4096,512] fp32 -> windows [1024, 64, 512]
//   qkv = xw @ Wqkv[512,1536]; per head (8 x 64d): S = QK^T/8, causal mask,
//   softmax, softmax AGAIN (no re-mask), out = P2 @ V; concat; @ Wproj + bproj.
//
// R14 pipeline (4 dispatches):
//   prep_weights, prep_x -> gemmQKV (Q,K,V in one 1536x65536 GEMM) ->
//   attn_proj (attention + output projection fused, no hP intermediate)
//
// FP(R) packing of M[r][k], k in [0,512):
//   pos(r,k) = ((r>>4)*16 + (k>>5))*512 + (((k>>3)&3)*16 + (r&15))*8 + (k&7)
//
// R6-R13 lesson: the 2-barrier GEMM K-loop is at its documented ~830-900 TF
// structural ceiling (m97/m98); five schedule variants all null. R14 attacks
// pipeline overhead instead: one fewer GEMM dispatch and the 134 MB hP
// round-trip + gemm<2> dispatch removed by fusing proj into the attn block
// (each window block owns complete hOut[64][512]).

typedef _Float16 f16x8 __attribute__((ext_vector_type(8)));
typedef _Float16 f16x4 __attribute__((ext_vector_type(4)));
typedef float f32x4 __attribute__((ext_vector_type(4)));

#define MFMA16(a, b, c) __builtin_amdgcn_mfma_f32_16x16x32_f16((a), (b), (c), 0, 0, 0)

__device__ __forceinline__ int swz512(int r, int c) { return r * 512 + (c ^ ((r & 7) << 3)); }
__device__ __forceinline__ int swz64(int r, int c) { return r * 64 + (c ^ ((r & 7) << 3)); }

typedef const __attribute__((address_space(1))) void* gas1_t;
typedef __attribute__((address_space(3))) void* las3_t;

__device__ __forceinline__ void stage16(const _Float16* g, _Float16* lbase, int lane) {
#if __has_builtin(__builtin_amdgcn_global_load_lds)
  __builtin_amdgcn_global_load_lds((gas1_t)(const void*)g, (las3_t)(void*)lbase, 16, 0, 0);
#else
  *(f16x8*)(lbase + lane * 8) = *(const f16x8*)g;
#endif
}

// ---------------------------------------------------------------------------
// prep_weights: wqkvP = FP(Wqkv^T) rows 0..1535 (Q rows scaled 0.125);
//               wprojP = FP(Wproj^T) rows 0..511.
// ---------------------------------------------------------------------------
__global__ void prep_weights(const float* __restrict__ Wqkv,
                             const float* __restrict__ Wproj,
                             _Float16* __restrict__ wqkvP,
                             _Float16* __restrict__ wprojP) {
  int idx = blockIdx.x * blockDim.x + threadIdx.x;
  if (idx < 786432) {
    int r16 = idx >> 13;
    int rem = idx & 8191;
    int kt = rem >> 9;
    int lane = (rem >> 3) & 63;
    int e = rem & 7;
    int row = r16 * 16 + (lane & 15);
    int k = kt * 32 + (lane >> 4) * 8 + e;
    float v = Wqkv[k * 1536 + row];
    if (row < 512) v *= 0.125f;
    wqkvP[idx] = (_Float16)v;
  } else {
    int j = idx - 786432;
    int r16 = j >> 13;
    int rem = j & 8191;
    int kt = rem >> 9;
    int lane = (rem >> 3) & 63;
    int e = rem & 7;
    int n = r16 * 16 + (lane & 15);
    int k = kt * 32 + (lane >> 4) * 8 + e;
    wprojP[j] = (_Float16)Wproj[k * 512 + n];
  }
}

// ---------------------------------------------------------------------------
// prep_x: xP = FP(x fp16, 65536 rows)
// ---------------------------------------------------------------------------
__global__ __launch_bounds__(512) void prep_x(const float* __restrict__ x,
                                              _Float16* __restrict__ xP) {
  __shared__ __align__(16) _Float16 sX[64 * 512];
  const int tid = threadIdx.x;
  const float4* xv = (const float4*)(x + (size_t)blockIdx.x * 32768);
#pragma unroll
  for (int it = 0; it < 8; ++it) {
    int g = tid + it * 512;
    int r = g >> 6, c0 = (g & 63) << 3;
    float4 a = xv[(r << 7) + (c0 >> 2)];
    float4 b = xv[(r << 7) + (c0 >> 2) + 1];
    f16x8 hv;
    hv[0] = (_Float16)a.x; hv[1] = (_Float16)a.y;
    hv[2] = (_Float16)a.z; hv[3] = (_Float16)a.w;
    hv[4] = (_Float16)b.x; hv[5] = (_Float16)b.y;
    hv[6] = (_Float16)b.z; hv[7] = (_Float16)b.w;
    *(f16x8*)&sX[swz512(r, c0)] = hv;
  }
  __syncthreads();
  _Float16* dst = xP + (size_t)blockIdx.x * 32768;
#pragma unroll
  for (int it = 0; it < 8; ++it) {
    int c8 = tid + it * 512;
    int rt = c8 >> 10, ks = (c8 >> 6) & 15, ln = c8 & 63;
    int row = rt * 16 + (ln & 15);
    int k0 = ks * 32 + (ln >> 4) * 8;
    f16x8 v = *(const f16x8*)&sX[swz512(row, k0)];
    *(f16x8*)(dst + c8 * 8) = v;
  }
}

// ---------------------------------------------------------------------------
// gemmQKV: D[n][t] = sum_k Wqkv^T[n,k] xP[t,k], n in [0,1536), t in [0,65536).
// 256x256 tile, BK=32, K=512. 8 waves; wave owns 128x64 (acc 8x4). 64KB LDS.
// Epilogue: n<1024 -> Q/K scatter (8B vec); n>=1024 -> V^T scatter (4x2B).
// ---------------------------------------------------------------------------
__global__ __launch_bounds__(512, 2) void gemmQKV(
    const _Float16* __restrict__ Afp, const _Float16* __restrict__ Bfp,
    _Float16* __restrict__ dst16) {
  __shared__ __align__(16) _Float16 sG[2][2][16][512];
  const int tid = threadIdx.x;
  const int wid = tid >> 6;
  const int lane = tid & 63;
  const int lg = lane >> 4, lr = lane & 15;
  const int wr = wid >> 2, wc = wid & 3;
  const int wr8 = wr * 8, wc4 = wc * 4, lane8 = lane * 8;
  const int cs = wid * 2;

  // XCD-chunked bijective swizzle (nwg = 1536, % 8 == 0)
  const int nwg = gridDim.x;
  const int bid = blockIdx.x;
  const int swz = (bid & 7) * (nwg >> 3) + (bid >> 3);
  const int r0 = (swz % 6) * 256, c0 = (swz / 6) * 256;

  const _Float16* Abase = Afp + (size_t)(r0 >> 4) * 8192 + lane8;
  const _Float16* Bbase = Bfp + (size_t)(c0 >> 4) * 8192 + lane8;

  auto STAGE = [&](int s, int T) {
    stage16(Abase + (size_t)cs * 8192 + T * 512, &sG[s][0][cs][0], lane);
    stage16(Abase + (size_t)(cs + 1) * 8192 + T * 512, &sG[s][0][cs + 1][0], lane);
    stage16(Bbase + (size_t)cs * 8192 + T * 512, &sG[s][1][cs][0], lane);
    stage16(Bbase + (size_t)(cs + 1) * 8192 + T * 512, &sG[s][1][cs + 1][0], lane);
  };

  const f32x4 zero4 = {0.f, 0.f, 0.f, 0.f};
  f32x4 acc[8][4];
#pragma unroll
  for (int i = 0; i < 8; ++i)
#pragma unroll
    for (int j = 0; j < 4; ++j) acc[i][j] = zero4;

  STAGE(0, 0);
  int cur = 0;
  for (int t = 0; t < 16; ++t) {
    const int Tn = (t + 1 < 16) ? t + 1 : 15;
    STAGE(cur ^ 1, Tn);
    asm volatile("s_waitcnt vmcnt(4)");
    __builtin_amdgcn_s_barrier();
    __builtin_amdgcn_sched_barrier(0);
    f16x8 a[8], b[4];
#pragma unroll
    for (int mi = 0; mi < 8; ++mi)
      a[mi] = *(const f16x8*)&sG[cur][0][wr8 + mi][lane8];
#pragma unroll
    for (int ni = 0; ni < 4; ++ni)
      b[ni] = *(const f16x8*)&sG[cur][1][wc4 + ni][lane8];
    __builtin_amdgcn_s_setprio(1);
#pragma unroll
    for (int mi = 0; mi < 8; ++mi)
#pragma unroll
      for (int ni = 0; ni < 4; ++ni)
        acc[mi][ni] = MFMA16(a[mi], b[ni], acc[mi][ni]);
    __builtin_amdgcn_s_setprio(0);
    asm volatile("s_waitcnt lgkmcnt(0)");
    __builtin_amdgcn_sched_barrier(0);
    __builtin_amdgcn_s_barrier();
    __builtin_amdgcn_sched_barrier(0);
    cur ^= 1;
  }

#pragma unroll
  for (int mi = 0; mi < 8; ++mi) {
    int nb = r0 + wr * 128 + mi * 16 + lg * 4;
    if (nb < 1024) {
      int sec = nb >> 9, h = (nb >> 6) & 7, db = nb & 63;
      int coff = (db >> 5) * 512 + (((db >> 3) & 3) * 16) * 8 + (db & 7);
#pragma unroll
      for (int ni = 0; ni < 4; ++ni) {
        int tg = c0 + wc * 64 + ni * 16 + lr;
        int w = tg >> 6, t = tg & 63;
        size_t pos = ((size_t)w * 24 + sec * 8 + h) * 4096 +
                     (size_t)((t >> 4) * 2) * 512 + coff + (t & 15) * 8;
        f16x4 hv;
        hv[0] = (_Float16)acc[mi][ni][0]; hv[1] = (_Float16)acc[mi][ni][1];
        hv[2] = (_Float16)acc[mi][ni][2]; hv[3] = (_Float16)acc[mi][ni][3];
        *(f16x4*)(dst16 + pos) = hv;
      }
    } else {
      // V: D[n][t] = V^T[d][t] per head. FP rows=d, k=t.
      int h = (nb >> 6) & 7, db = nb & 63;  // db = d base (lg*4 within 16)
#pragma unroll
      for (int ni = 0; ni < 4; ++ni) {
        int tg = c0 + wc * 64 + ni * 16 + lr;
        int w = tg >> 6, t = tg & 63;
        size_t base2 = ((size_t)w * 24 + 16 + h) * 4096 +
                       (size_t)((db >> 4) * 2 + (t >> 5)) * 512 +
                       (((t >> 3) & 3) * 16) * 8 + (t & 7);
#pragma unroll
        for (int rg = 0; rg < 4; ++rg)
          dst16[base2 + ((db & 15) + rg) * 8] = (_Float16)acc[mi][ni][rg];
      }
    }
  }
}

// ---------------------------------------------------------------------------
// attn_proj: 1 block = 1 window, 512 thr, LDS 16KB.
// Per head pair hp: attention (4 waves/head, 16 q-rows each; Q/K/V fragments
// from qkvP global) -> out_h in sPO; then proj accumulate accO += Wproj x PO.
// Epilogue: out[t][n] float4 stores + bias.
// ---------------------------------------------------------------------------
__global__ __launch_bounds__(512, 2) void attn_proj(
    const _Float16* __restrict__ qkvP, const _Float16* __restrict__ wprojP,
    const float* __restrict__ bproj, float* __restrict__ out) {
  __shared__ __align__(16) _Float16 sPO[2][4096];  // per-head P then out_h
  const int tid = threadIdx.x;
  const int wid = tid >> 6;
  const int lane = tid & 63;
  const int lg = lane >> 4, lr = lane & 15;
  const int w = blockIdx.x;
  const f32x4 zero4 = {0.f, 0.f, 0.f, 0.f};

  f32x4 accO[4][4];  // [nt = n-tile within wave's 64 cols][tt = token tile]
#pragma unroll
  for (int i = 0; i < 4; ++i)
#pragma unroll
    for (int j = 0; j < 4; ++j) accO[i][j] = zero4;

  for (int hp = 0; hp < 4; ++hp) {
    // ===== attention for heads 2hp, 2hp+1 (wave = (hh, rs)) ================
    {
      const int hh = wid >> 2;
      const int rs = wid & 3;
      const int h = hp * 2 + hh;
      const _Float16* Qb = qkvP + ((size_t)w * 24 + h) * 4096 + lane * 8;
      const _Float16* Kb = qkvP + ((size_t)w * 24 + 8 + h) * 4096 + lane * 8;
      const _Float16* Vb = qkvP + ((size_t)w * 24 + 16 + h) * 4096 + lane * 8;
      _Float16* mP = &sPO[hh][0];

      f32x4 sacc[4];
#pragma unroll
      for (int nt = 0; nt < 4; ++nt) sacc[nt] = zero4;
#pragma unroll
      for (int dkt = 0; dkt < 2; ++dkt) {
        f16x8 afq = *(const f16x8*)(Qb + (rs * 2 + dkt) * 512);
#pragma unroll
        for (int nt = 0; nt < 4; ++nt) {
          f16x8 bfk = *(const f16x8*)(Kb + (nt * 2 + dkt) * 512);
          sacc[nt] = MFMA16(afq, bfk, sacc[nt]);
        }
      }
      float p2[4][4];
#pragma unroll
      for (int rg = 0; rg < 4; ++rg) {
        int row = rs * 16 + lg * 4 + rg;
        float m = -1e30f;
#pragma unroll
        for (int nt = 0; nt < 4; ++nt) {
          int col = nt * 16 + lr;
          float v = (col <= row) ? sacc[nt][rg] : -1e30f;
          m = fmaxf(m, v);
        }
#pragma unroll
        for (int off = 8; off >= 1; off >>= 1) m = fmaxf(m, __shfl_xor(m, off));
        float e[4], s1 = 0.f;
#pragma unroll
        for (int nt = 0; nt < 4; ++nt) {
          int col = nt * 16 + lr;
          e[nt] = (col <= row) ? __expf(sacc[nt][rg] - m) : 0.f;
          s1 += e[nt];
        }
#pragma unroll
        for (int off = 8; off >= 1; off >>= 1) s1 += __shfl_xor(s1, off);
        float inv1 = 1.f / s1;
        float e2[4], s2 = 0.f;
#pragma unroll
        for (int nt = 0; nt < 4; ++nt) {
          e2[nt] = __expf(e[nt] * inv1);
          s2 += e2[nt];
        }
#pragma unroll
        for (int off = 8; off >= 1; off >>= 1) s2 += __shfl_xor(s2, off);
        float inv2 = 1.f / s2;
#pragma unroll
        for (int nt = 0; nt < 4; ++nt) p2[nt][rg] = e2[nt] * inv2;
      }
#pragma unroll
      for (int nt = 0; nt < 4; ++nt)
#pragma unroll
        for (int rg = 0; rg < 4; ++rg)
          mP[swz64(rs * 16 + lg * 4 + rg, nt * 16 + lr)] = (_Float16)p2[nt][rg];
      asm volatile("" ::: "memory");
      f32x4 oacc[4];
#pragma unroll
      for (int nt = 0; nt < 4; ++nt) oacc[nt] = zero4;
#pragma unroll
      for (int tkt = 0; tkt < 2; ++tkt) {
        f16x8 afp = *(const f16x8*)&mP[swz64(rs * 16 + lr, tkt * 32 + lg * 8)];
#pragma unroll
        for (int nt = 0; nt < 4; ++nt) {
          f16x8 bfv = *(const f16x8*)(Vb + (nt * 2 + tkt) * 512);
          oacc[nt] = MFMA16(afp, bfv, oacc[nt]);
        }
      }
      asm volatile("" ::: "memory");
#pragma unroll
      for (int nt = 0; nt < 4; ++nt)
#pragma unroll
        for (int rg = 0; rg < 4; ++rg)
          mP[swz64(rs * 16 + lg * 4 + rg, nt * 16 + lr)] = (_Float16)oacc[nt][rg];
    }
    __syncthreads();  // both heads' out_h ready in sPO

    // ===== proj accumulate: accO[nt][tt] += Wproj frag x PO frag ============
    // wave owns n cols [wid*64, +64); k for this hp = 128 (2 heads x 64 d).
#pragma unroll
    for (int ks = 0; ks < 4; ++ks) {  // k-step of 32 within the pair
      const int hh = ks >> 1, d0 = (ks & 1) * 32 + lg * 8;
      f16x8 bf[4];
#pragma unroll
      for (int tt = 0; tt < 4; ++tt)
        bf[tt] = *(const f16x8*)&sPO[hh][swz64(tt * 16 + lr, d0)];
#pragma unroll
      for (int nt = 0; nt < 4; ++nt) {
        f16x8 aw = *(const f16x8*)(wprojP + (size_t)(wid * 4 + nt) * 8192 +
                                   (size_t)(hp * 4 + ks) * 512 + lane * 8);
#pragma unroll
        for (int tt = 0; tt < 4; ++tt)
          accO[nt][tt] = MFMA16(aw, bf[tt], accO[nt][tt]);
      }
    }
    __syncthreads();  // sPO safe to overwrite next hp
  }

  // ===== epilogue: out[t][n] = accO + bias, float4 along n ================
#pragma unroll
  for (int nt = 0; nt < 4; ++nt) {
    int nb = wid * 64 + nt * 16 + lg * 4;
    float4 bi = *(const float4*)&bproj[nb];
#pragma unroll
    for (int tt = 0; tt < 4; ++tt) {
      int tok = tt * 16 + lr;
      float4 v;
      v.x = accO[nt][tt][0] + bi.x; v.y = accO[nt][tt][1] + bi.y;
      v.z = accO[nt][tt][2] + bi.z; v.w = accO[nt][tt][3] + bi.w;
      *(float4*)&out[((size_t)w * 64 + tok) * 512 + nb] = v;
    }
  }
}

// ---------------------------------------------------------------------------
// Fallback (verified R2 kernel) for small workspaces: fused, 128 KB LDS.
// ---------------------------------------------------------------------------
__global__ __launch_bounds__(512, 2) void attn_fused(
    const float* __restrict__ x, const _Float16* __restrict__ wqkvP,
    const _Float16* __restrict__ wprojP, const float* __restrict__ bproj,
    float* __restrict__ out) {
  __shared__ __align__(16) _Float16 sX[64 * 512];
  __shared__ __align__(16) _Float16 sHeads[4][2][4096];

  const int tid = threadIdx.x;
  const int wid = tid >> 6;
  const int lane = tid & 63;
  const int lg = lane >> 4;
  const int lr = lane & 15;

  _Float16* sQ0 = &sHeads[0][0][0];
  _Float16* sK0 = &sHeads[1][0][0];
  _Float16* sVT0 = &sHeads[2][0][0];
  _Float16* sPO0 = &sHeads[3][0][0];

  const float4* xv = (const float4*)(x + (size_t)blockIdx.x * 32768);
#pragma unroll
  for (int it = 0; it < 8; ++it) {
    int g = tid + it * 512;
    int r = g >> 6, c0 = (g & 63) << 3;
    float4 a = xv[(r << 7) + (c0 >> 2)];
    float4 b = xv[(r << 7) + (c0 >> 2) + 1];
    f16x8 hv;
    hv[0] = (_Float16)a.x; hv[1] = (_Float16)a.y;
    hv[2] = (_Float16)a.z; hv[3] = (_Float16)a.w;
    hv[4] = (_Float16)b.x; hv[5] = (_Float16)b.y;
    hv[6] = (_Float16)b.z; hv[7] = (_Float16)b.w;
    *(f16x8*)&sX[swz512(r, c0)] = hv;
  }
  const f32x4 zero4 = {0.f, 0.f, 0.f, 0.f};
  f32x4 accO[4][4];
#pragma unroll
  for (int i = 0; i < 4; ++i)
#pragma unroll
    for (int j = 0; j < 4; ++j) accO[i][j] = zero4;
  __syncthreads();

  for (int hp = 0; hp < 4; ++hp) {
    int hu[3], su[3], stu[3];
    const _Float16* bp[3];
    f32x4 acc[3][4];
#pragma unroll
    for (int i = 0; i < 3; ++i) {
      int u = wid + 8 * i;
      int hh = u & 1, v2 = u >> 1;
      int sec = v2 % 3, strip = v2 / 3;
      hu[i] = hh; su[i] = sec; stu[i] = strip;
      int r16 = sec * 32 + (hp * 2 + hh) * 4 + strip;
      bp[i] = wqkvP + (size_t)r16 * 8192 + lane * 8;
#pragma unroll
      for (int rt = 0; rt < 4; ++rt) acc[i][rt] = zero4;
    }
    f16x8 bf[3][3];
#pragma unroll
    for (int d = 0; d < 3; ++d)
#pragma unroll
      for (int i = 0; i < 3; ++i) bf[d][i] = *(const f16x8*)(bp[i] + d * 512);
    f16x8 af[2][4];
#pragma unroll
    for (int rt = 0; rt < 4; ++rt)
      af[0][rt] = *(const f16x8*)&sX[swz512(rt * 16 + lr, lg * 8)];
#pragma unroll
    for (int ks = 0; ks < 16; ++ks) {
      if (ks < 15) {
#pragma unroll
        for (int rt = 0; rt < 4; ++rt)
          af[(ks + 1) & 1][rt] =
              *(const f16x8*)&sX[swz512(rt * 16 + lr, (ks + 1) * 32 + lg * 8)];
      }
#pragma unroll
      for (int i = 0; i < 3; ++i)
#pragma unroll
        for (int rt = 0; rt < 4; ++rt)
          acc[i][rt] = MFMA16(af[ks & 1][rt], bf[ks % 3][i], acc[i][rt]);
      if (ks + 3 < 16) {
#pragma unroll
        for (int i = 0; i < 3; ++i)
          bf[ks % 3][i] = *(const f16x8*)(bp[i] + (ks + 3) * 512);
      }
    }
#pragma unroll
    for (int i = 0; i < 3; ++i) {
      int hh = hu[i], sec = su[i], strip = stu[i];
      _Float16* dq = sQ0 + hh * 4096;
      _Float16* dk = sK0 + hh * 4096;
      _Float16* dv = sVT0 + hh * 4096;
#pragma unroll
      for (int rt = 0; rt < 4; ++rt)
#pragma unroll
        for (int rg = 0; rg < 4; ++rg) {
          int row = rt * 16 + lg * 4 + rg;
          int col = strip * 16 + lr;
          _Float16 v = (_Float16)acc[i][rt][rg];
          if (sec == 0) dq[swz64(row, col)] = v;
          else if (sec == 1) dk[swz64(row, col)] = v;
          else dv[swz64(col, row)] = v;
        }
    }
    __syncthreads();
    {
      const int hh = wid >> 2;
      const int rs = wid & 3;
      const _Float16* mQ = sQ0 + hh * 4096;
      const _Float16* mK = sK0 + hh * 4096;
      const _Float16* mV = sVT0 + hh * 4096;
      _Float16* mP = sPO0 + hh * 4096;
      f32x4 sacc[4];
#pragma unroll
      for (int nt = 0; nt < 4; ++nt) sacc[nt] = zero4;
#pragma unroll
      for (int ks = 0; ks < 2; ++ks) {
        f16x8 afq = *(const f16x8*)&mQ[swz64(rs * 16 + lr, ks * 32 + lg * 8)];
#pragma unroll
        for (int nt = 0; nt < 4; ++nt) {
          f16x8 bfk = *(const f16x8*)&mK[swz64(nt * 16 + lr, ks * 32 + lg * 8)];
          sacc[nt] = MFMA16(afq, bfk, sacc[nt]);
        }
      }
      float p2[4][4];
#pragma unroll
      for (int rg = 0; rg < 4; ++rg) {
        int row = rs * 16 + lg * 4 + rg;
        float m = -1e30f;
#pragma unroll
        for (int nt = 0; nt < 4; ++nt) {
          int col = nt * 16 + lr;
          float v = (col <= row) ? sacc[nt][rg] : -1e30f;
          m = fmaxf(m, v);
        }
#pragma unroll
        for (int off = 8; off >= 1; off >>= 1) m = fmaxf(m, __shfl_xor(m, off));
        float e[4], s1 = 0.f;
#pragma unroll
        for (int nt = 0; nt < 4; ++nt) {
          int col = nt * 16 + lr;
          e[nt] = (col <= row) ? __expf(sacc[nt][rg] - m) : 0.f;
          s1 += e[nt];
        }
#pragma unroll
        for (int off = 8; off >= 1; off >>= 1) s1 += __shfl_xor(s1, off);
        float inv1 = 1.f / s1;
        float e2[4], s2 = 0.f;
#pragma unroll
        for (int nt = 0; nt < 4; ++nt) {
          e2[nt] = __expf(e[nt] * inv1);
          s2 += e2[nt];
        }
#pragma unroll
        for (int off = 8; off >= 1; off >>= 1) s2 += __shfl_xor(s2, off);
        float inv2 = 1.f / s2;
#pragma unroll
        for (int nt = 0; nt < 4; ++nt) p2[nt][rg] = e2[nt] * inv2;
      }
#pragma unroll
      for (int nt = 0; nt < 4; ++nt)
#pragma unroll
        for (int rg = 0; rg < 4; ++rg)
          mP[swz64(rs * 16 + lg * 4 + rg, nt * 16 + lr)] = (_Float16)p2[nt][rg];
      asm volatile("" ::: "memory");
      f32x4 oacc[4];
#pragma unroll
      for (int nt = 0; nt < 4; ++nt) oacc[nt] = zero4;
#pragma unroll
      for (int ks = 0; ks < 2; ++ks) {
        f16x8 afp = *(const f16x8*)&mP[swz64(rs * 16 + lr, ks * 32 + lg * 8)];
#pragma unroll
        for (int nt = 0; nt < 4; ++nt) {
          f16x8 bfv = *(const f16x8*)&mV[swz64(nt * 16 + lr, ks * 32 + lg * 8)];
          oacc[nt] = MFMA16(afp, bfv, oacc[nt]);
        }
      }
      asm volatile("" ::: "memory");
#pragma unroll
      for (int nt = 0; nt < 4; ++nt)
#pragma unroll
        for (int rg = 0; rg < 4; ++rg)
          mP[swz64(rs * 16 + lg * 4 + rg, nt * 16 + lr)] = (_Float16)oacc[nt][rg];
    }
    __syncthreads();
    {
      f16x8 bfC[2][4], afC[2][4];
#pragma unroll
      for (int rt = 0; rt < 4; ++rt)
        afC[0][rt] = *(const f16x8*)&sPO0[swz64(rt * 16 + lr, lg * 8)];
#pragma unroll
      for (int nt = 0; nt < 4; ++nt)
        bfC[0][nt] = *(const f16x8*)(wprojP + (size_t)(wid * 4 + nt) * 8192 +
                                     (size_t)(hp * 4) * 512 + lane * 8);
#pragma unroll
      for (int g = 0; g < 4; ++g) {
        if (g < 3) {
          int hn = (g + 1) >> 1, kn = (g + 1) & 1;
#pragma unroll
          for (int rt = 0; rt < 4; ++rt)
            afC[(g + 1) & 1][rt] = *(const f16x8*)&sPO0[hn * 4096 +
                swz64(rt * 16 + lr, kn * 32 + lg * 8)];
#pragma unroll
          for (int nt = 0; nt < 4; ++nt)
            bfC[(g + 1) & 1][nt] =
                *(const f16x8*)(wprojP + (size_t)(wid * 4 + nt) * 8192 +
                                (size_t)(hp * 4 + g + 1) * 512 + lane * 8);
        }
#pragma unroll
        for (int nt = 0; nt < 4; ++nt)
#pragma unroll
          for (int rt = 0; rt < 4; ++rt)
            accO[rt][nt] = MFMA16(afC[g & 1][rt], bfC[g & 1][nt], accO[rt][nt]);
      }
    }
  }
  __syncthreads();
  float bias_r[4];
#pragma unroll
  for (int nt = 0; nt < 4; ++nt) bias_r[nt] = bproj[wid * 64 + nt * 16 + lr];
  float* sEp = (float*)&sHeads[0][0][0];
  size_t base = (size_t)blockIdx.x * 32768;
#pragma unroll
  for (int half = 0; half < 2; ++half) {
#pragma unroll
    for (int rr = 0; rr < 2; ++rr) {
      int rt = half * 2 + rr;
#pragma unroll
      for (int nt = 0; nt < 4; ++nt)
#pragma unroll
        for (int rg = 0; rg < 4; ++rg) {
          int r = rr * 16 + lg * 4 + rg;
          int c = wid * 64 + nt * 16 + lr;
          sEp[r * 512 + (c ^ (((r >> 2) & 1) << 4))] = accO[rt][nt][rg] + bias_r[nt];
        }
    }
    __syncthreads();
#pragma unroll
    for (int j = 0; j < 8; ++j) {
      int f4 = tid + j * 512;
      int r = f4 >> 7;
      int c0 = (f4 & 127) << 2;
      float4 v = *(const float4*)&sEp[r * 512 + (c0 ^ (((r >> 2) & 1) << 4))];
      *(float4*)&out[base + (size_t)(half * 32 + r) * 512 + c0] = v;
    }
    if (half == 0) __syncthreads();
  }
}

extern "C" void kernel_launch(void* const* d_in, const int* in_sizes, int n_in,
                              void* d_out, int out_size, void* d_ws, size_t ws_size,
                              hipStream_t stream) {
  const float* x = (const float*)d_in[0];
  const float* Wqkv = (const float*)d_in[1];
  const float* Wproj = (const float*)d_in[2];
  const float* bproj = (const float*)d_in[3];
  float* out = (float*)d_out;

  const size_t W1 = 786432, W2 = 262144, XN = 33554432, QN = 100663296;
  _Float16* wqkvP = (_Float16*)d_ws;
  _Float16* wprojP = wqkvP + W1;
  _Float16* xP = wprojP + W2;
  _Float16* qkvP = xP + XN;
  const size_t NEED = (W1 + W2 + XN + QN) * 2;

  prep_weights<<<dim3(4096), dim3(256), 0, stream>>>(Wqkv, Wproj, wqkvP, wprojP);
  if (ws_size >= NEED) {
    prep_x<<<dim3(1024), dim3(512), 0, stream>>>(x, xP);
    // Q,K,V in one GEMM: A = Wqkv^T rows (6 tiles), B = xP tokens (256 tiles)
    gemmQKV<<<dim3(1536), dim3(512), 0, stream>>>(wqkvP, xP, qkvP);
    attn_proj<<<dim3(1024), dim3(512), 0, stream>>>(qkvP, wprojP, bproj, out);
  } else {
    attn_fused<<<dim3(1024), dim3(512), 0, stream>>>(x, wqkvP, wprojP, bproj, out);
  }
}

// Round 15
// 294.713 us; speedup vs baseline: 1.0219x; 1.0219x over previous
//
#include <hip/hip_runtime.h>

// x[16,4096,512] fp32 -> windows [1024, 64, 512]
//   qkv = xw @ Wqkv[512,1536]; per head (8 x 64d): S = QK^T/8, causal mask,
//   softmax, softmax AGAIN (no re-mask), out = P2 @ V; concat; @ Wproj + bproj.
//
// R15 pipeline (5 dispatches):
//   prep_weights, prep_x -> gemm128<0> (QKV, one 1536x65536 GEMM) ->
//   attn_win -> gemm128<2> (proj)
//
// FP(R) packing of M[r][k], k in [0,512):
//   pos(r,k) = ((r>>4)*16 + (k>>5))*512 + (((k>>3)&3)*16 + (r&15))*8 + (k&7)
//
// gemm128: m97-shape 128x128 tile (guide tile-space: 128^2=912 TF beats
// 256^2=792 TF for the 2-barrier structure -- more blocks/CU overlap the
// barrier drains). 256 thr / 4 waves / wave owns 64x64 (acc 4x4), BK=32,
// 32KB LDS (2 slots), counted vmcnt(4), no launch-bounds occupancy cap
// (R7 lesson: capping the allocator below the working set -> scratch spill).

typedef _Float16 f16x8 __attribute__((ext_vector_type(8)));
typedef _Float16 f16x4 __attribute__((ext_vector_type(4)));
typedef float f32x4 __attribute__((ext_vector_type(4)));

#define MFMA16(a, b, c) __builtin_amdgcn_mfma_f32_16x16x32_f16((a), (b), (c), 0, 0, 0)

__device__ __forceinline__ int swz512(int r, int c) { return r * 512 + (c ^ ((r & 7) << 3)); }
__device__ __forceinline__ int swz64(int r, int c) { return r * 64 + (c ^ ((r & 7) << 3)); }

typedef const __attribute__((address_space(1))) void* gas1_t;
typedef __attribute__((address_space(3))) void* las3_t;

__device__ __forceinline__ void stage16(const _Float16* g, _Float16* lbase, int lane) {
#if __has_builtin(__builtin_amdgcn_global_load_lds)
  __builtin_amdgcn_global_load_lds((gas1_t)(const void*)g, (las3_t)(void*)lbase, 16, 0, 0);
#else
  *(f16x8*)(lbase + lane * 8) = *(const f16x8*)g;
#endif
}

// ---------------------------------------------------------------------------
// prep_weights: wqkvP = FP(Wqkv^T) rows 0..1535 (Q rows scaled 0.125);
//               wprojP = FP(Wproj^T) rows 0..511.
// ---------------------------------------------------------------------------
__global__ void prep_weights(const float* __restrict__ Wqkv,
                             const float* __restrict__ Wproj,
                             _Float16* __restrict__ wqkvP,
                             _Float16* __restrict__ wprojP) {
  int idx = blockIdx.x * blockDim.x + threadIdx.x;
  if (idx < 786432) {
    int r16 = idx >> 13;
    int rem = idx & 8191;
    int kt = rem >> 9;
    int lane = (rem >> 3) & 63;
    int e = rem & 7;
    int row = r16 * 16 + (lane & 15);
    int k = kt * 32 + (lane >> 4) * 8 + e;
    float v = Wqkv[k * 1536 + row];
    if (row < 512) v *= 0.125f;
    wqkvP[idx] = (_Float16)v;
  } else {
    int j = idx - 786432;
    int r16 = j >> 13;
    int rem = j & 8191;
    int kt = rem >> 9;
    int lane = (rem >> 3) & 63;
    int e = rem & 7;
    int n = r16 * 16 + (lane & 15);
    int k = kt * 32 + (lane >> 4) * 8 + e;
    wprojP[j] = (_Float16)Wproj[k * 512 + n];
  }
}

// ---------------------------------------------------------------------------
// prep_x: xP = FP(x fp16, 65536 rows)
// ---------------------------------------------------------------------------
__global__ __launch_bounds__(512) void prep_x(const float* __restrict__ x,
                                              _Float16* __restrict__ xP) {
  __shared__ __align__(16) _Float16 sX[64 * 512];
  const int tid = threadIdx.x;
  const float4* xv = (const float4*)(x + (size_t)blockIdx.x * 32768);
#pragma unroll
  for (int it = 0; it < 8; ++it) {
    int g = tid + it * 512;
    int r = g >> 6, c0 = (g & 63) << 3;
    float4 a = xv[(r << 7) + (c0 >> 2)];
    float4 b = xv[(r << 7) + (c0 >> 2) + 1];
    f16x8 hv;
    hv[0] = (_Float16)a.x; hv[1] = (_Float16)a.y;
    hv[2] = (_Float16)a.z; hv[3] = (_Float16)a.w;
    hv[4] = (_Float16)b.x; hv[5] = (_Float16)b.y;
    hv[6] = (_Float16)b.z; hv[7] = (_Float16)b.w;
    *(f16x8*)&sX[swz512(r, c0)] = hv;
  }
  __syncthreads();
  _Float16* dst = xP + (size_t)blockIdx.x * 32768;
#pragma unroll
  for (int it = 0; it < 8; ++it) {
    int c8 = tid + it * 512;
    int rt = c8 >> 10, ks = (c8 >> 6) & 15, ln = c8 & 63;
    int row = rt * 16 + (ln & 15);
    int k0 = ks * 32 + (ln >> 4) * 8;
    f16x8 v = *(const f16x8*)&sX[swz512(row, k0)];
    *(f16x8*)(dst + c8 * 8) = v;
  }
}

// ---------------------------------------------------------------------------
// gemm128: D[i][j] = sum_k A[i,k] B[j,k]. 128x128 tile, BK=32, K=512.
// 4 waves (256 thr); wave (wr,wc) owns 64x64 (acc 4x4). 32KB LDS, 2 slots.
// MODE 0: A=Wqkv^T (1536 rows: Q,K then V), B=xP tokens -> qkvP packed
// MODE 2: A=Wproj^T rows, B=hP tokens -> out fp32 + bias
// ---------------------------------------------------------------------------
template <int MODE>
__global__ __launch_bounds__(256) void gemm128(
    const _Float16* __restrict__ Afp, const _Float16* __restrict__ Bfp,
    _Float16* __restrict__ dst16, float* __restrict__ out,
    const float* __restrict__ bproj, int rTiles) {
  __shared__ __align__(16) _Float16 sG[2][2][8][512];  // 32KB
  const int tid = threadIdx.x;
  const int wid = tid >> 6;            // 0..3
  const int lane = tid & 63;
  const int lg = lane >> 4, lr = lane & 15;
  const int wr = wid >> 1, wc = wid & 1;
  const int wr4 = wr * 4, wc4 = wc * 4, lane8 = lane * 8;
  const int cs = wid * 2;              // this wave's two chunk rows (0..7)

  // XCD-chunked bijective swizzle (nwg % 8 == 0 for both modes)
  const int nwg = gridDim.x;
  const int bid = blockIdx.x;
  const int swz = (bid & 7) * (nwg >> 3) + (bid >> 3);
  const int r0 = (swz % rTiles) * 128, c0 = (swz / rTiles) * 128;

  const _Float16* Abase = Afp + (size_t)(r0 >> 4) * 8192 + lane8;
  const _Float16* Bbase = Bfp + (size_t)(c0 >> 4) * 8192 + lane8;

  auto STAGE = [&](int s, int T) {
    stage16(Abase + (size_t)cs * 8192 + T * 512, &sG[s][0][cs][0], lane);
    stage16(Abase + (size_t)(cs + 1) * 8192 + T * 512, &sG[s][0][cs + 1][0], lane);
    stage16(Bbase + (size_t)cs * 8192 + T * 512, &sG[s][1][cs][0], lane);
    stage16(Bbase + (size_t)(cs + 1) * 8192 + T * 512, &sG[s][1][cs + 1][0], lane);
  };

  const f32x4 zero4 = {0.f, 0.f, 0.f, 0.f};
  f32x4 acc[4][4];
#pragma unroll
  for (int i = 0; i < 4; ++i)
#pragma unroll
    for (int j = 0; j < 4; ++j) acc[i][j] = zero4;

  STAGE(0, 0);
  int cur = 0;
  for (int t = 0; t < 16; ++t) {
    const int Tn = (t + 1 < 16) ? t + 1 : 15;  // tail re-stage: harmless
    STAGE(cur ^ 1, Tn);
    asm volatile("s_waitcnt vmcnt(4)");  // drain tile t; t+1 stays in flight
    __builtin_amdgcn_s_barrier();
    __builtin_amdgcn_sched_barrier(0);
    f16x8 a[4], b[4];
#pragma unroll
    for (int mi = 0; mi < 4; ++mi)
      a[mi] = *(const f16x8*)&sG[cur][0][wr4 + mi][lane8];
#pragma unroll
    for (int ni = 0; ni < 4; ++ni)
      b[ni] = *(const f16x8*)&sG[cur][1][wc4 + ni][lane8];
    __builtin_amdgcn_s_setprio(1);
#pragma unroll
    for (int mi = 0; mi < 4; ++mi)
#pragma unroll
      for (int ni = 0; ni < 4; ++ni)
        acc[mi][ni] = MFMA16(a[mi], b[ni], acc[mi][ni]);
    __builtin_amdgcn_s_setprio(0);
    asm volatile("s_waitcnt lgkmcnt(0)");
    __builtin_amdgcn_sched_barrier(0);
    __builtin_amdgcn_s_barrier();
    __builtin_amdgcn_sched_barrier(0);
    cur ^= 1;
  }

  // ============================ epilogue =================================
  if constexpr (MODE == 0) {
#pragma unroll
    for (int mi = 0; mi < 4; ++mi) {
      int nb = r0 + wr * 64 + mi * 16 + lg * 4;
      if (nb < 1024) {
        int sec = nb >> 9, h = (nb >> 6) & 7, db = nb & 63;
        int coff = (db >> 5) * 512 + (((db >> 3) & 3) * 16) * 8 + (db & 7);
#pragma unroll
        for (int ni = 0; ni < 4; ++ni) {
          int tg = c0 + wc * 64 + ni * 16 + lr;
          int w = tg >> 6, t = tg & 63;
          size_t pos = ((size_t)w * 24 + sec * 8 + h) * 4096 +
                       (size_t)((t >> 4) * 2) * 512 + coff + (t & 15) * 8;
          f16x4 hv;
          hv[0] = (_Float16)acc[mi][ni][0]; hv[1] = (_Float16)acc[mi][ni][1];
          hv[2] = (_Float16)acc[mi][ni][2]; hv[3] = (_Float16)acc[mi][ni][3];
          *(f16x4*)(dst16 + pos) = hv;
        }
      } else {
        // V: FP rows=d, k=t (verified R14 epilogue, re-indexed)
        int h = (nb >> 6) & 7, db = nb & 63;
#pragma unroll
        for (int ni = 0; ni < 4; ++ni) {
          int tg = c0 + wc * 64 + ni * 16 + lr;
          int w = tg >> 6, t = tg & 63;
          size_t base2 = ((size_t)w * 24 + 16 + h) * 4096 +
                         (size_t)((db >> 4) * 2 + (t >> 5)) * 512 +
                         (((t >> 3) & 3) * 16) * 8 + (t & 7);
#pragma unroll
          for (int rg = 0; rg < 4; ++rg)
            dst16[base2 + ((db & 15) + rg) * 8] = (_Float16)acc[mi][ni][rg];
        }
      }
    }
  } else {
#pragma unroll
    for (int mi = 0; mi < 4; ++mi) {
      int nb = r0 + wr * 64 + mi * 16 + lg * 4;
      float4 bi = *(const float4*)&bproj[nb];
#pragma unroll
      for (int ni = 0; ni < 4; ++ni) {
        int tg = c0 + wc * 64 + ni * 16 + lr;
        float4 v;
        v.x = acc[mi][ni][0] + bi.x; v.y = acc[mi][ni][1] + bi.y;
        v.z = acc[mi][ni][2] + bi.z; v.w = acc[mi][ni][3] + bi.w;
        *(float4*)&out[(size_t)tg * 512 + nb] = v;
      }
    }
  }
}

// ---------------------------------------------------------------------------
// attn_win: 1 block = 1 window, 512 thr. 2 rounds x 4 heads; wave=(head,part).
// (verified R5)
// ---------------------------------------------------------------------------
__global__ __launch_bounds__(512, 4) void attn_win(
    const _Float16* __restrict__ qkvP, _Float16* __restrict__ hP) {
  __shared__ __align__(16) _Float16 sP[4][4096];
  const int tid = threadIdx.x;
  const int wid = tid >> 6;
  const int lane = tid & 63;
  const int lg = lane >> 4, lr = lane & 15;
  const int hl = wid >> 1, part = wid & 1;
  const int w = blockIdx.x;
  const f32x4 zero4 = {0.f, 0.f, 0.f, 0.f};

  for (int hr = 0; hr < 2; ++hr) {
    const int h = hr * 4 + hl;
    const _Float16* Qb = qkvP + ((size_t)w * 24 + h) * 4096 + lane * 8;
    const _Float16* Kb = qkvP + ((size_t)w * 24 + 8 + h) * 4096 + lane * 8;
    const _Float16* Vb = qkvP + ((size_t)w * 24 + 16 + h) * 4096 + lane * 8;

    f16x8 afq[2][2], bfk[4][2];
#pragma unroll
    for (int rs = 0; rs < 2; ++rs)
#pragma unroll
      for (int dkt = 0; dkt < 2; ++dkt)
        afq[rs][dkt] = *(const f16x8*)(Qb + ((part * 2 + rs) * 2 + dkt) * 512);
#pragma unroll
    for (int nt = 0; nt < 4; ++nt)
#pragma unroll
      for (int dkt = 0; dkt < 2; ++dkt)
        bfk[nt][dkt] = *(const f16x8*)(Kb + (nt * 2 + dkt) * 512);
    f32x4 sacc[2][4];
#pragma unroll
    for (int rs = 0; rs < 2; ++rs)
#pragma unroll
      for (int nt = 0; nt < 4; ++nt) sacc[rs][nt] = zero4;
#pragma unroll
    for (int dkt = 0; dkt < 2; ++dkt)
#pragma unroll
      for (int rs = 0; rs < 2; ++rs)
#pragma unroll
        for (int nt = 0; nt < 4; ++nt)
          sacc[rs][nt] = MFMA16(afq[rs][dkt], bfk[nt][dkt], sacc[rs][nt]);

    f16x8 afv[2][2];
#pragma unroll
    for (int ds = 0; ds < 2; ++ds)
#pragma unroll
      for (int tkt = 0; tkt < 2; ++tkt)
        afv[ds][tkt] = *(const f16x8*)(Vb + ((part * 2 + ds) * 2 + tkt) * 512);

    float p2[2][4][4];
#pragma unroll
    for (int rs = 0; rs < 2; ++rs) {
      const int rsg = part * 2 + rs;
#pragma unroll
      for (int rg = 0; rg < 4; ++rg) {
        int row = rsg * 16 + lg * 4 + rg;
        float m = -1e30f;
#pragma unroll
        for (int nt = 0; nt < 4; ++nt) {
          int col = nt * 16 + lr;
          float v = (col <= row) ? sacc[rs][nt][rg] : -1e30f;
          m = fmaxf(m, v);
        }
#pragma unroll
        for (int off = 8; off >= 1; off >>= 1) m = fmaxf(m, __shfl_xor(m, off));
        float e[4], s1 = 0.f;
#pragma unroll
        for (int nt = 0; nt < 4; ++nt) {
          int col = nt * 16 + lr;
          e[nt] = (col <= row) ? __expf(sacc[rs][nt][rg] - m) : 0.f;
          s1 += e[nt];
        }
#pragma unroll
        for (int off = 8; off >= 1; off >>= 1) s1 += __shfl_xor(s1, off);
        float inv1 = 1.f / s1;
        float e2[4], s2 = 0.f;
#pragma unroll
        for (int nt = 0; nt < 4; ++nt) {
          e2[nt] = __expf(e[nt] * inv1);
          s2 += e2[nt];
        }
#pragma unroll
        for (int off = 8; off >= 1; off >>= 1) s2 += __shfl_xor(s2, off);
        float inv2 = 1.f / s2;
#pragma unroll
        for (int nt = 0; nt < 4; ++nt) p2[rs][nt][rg] = e2[nt] * inv2;
      }
    }

#pragma unroll
    for (int rs = 0; rs < 2; ++rs) {
      const int rsg = part * 2 + rs;
#pragma unroll
      for (int nt = 0; nt < 4; ++nt) {
        int cbase = (rsg * 2 + (nt >> 1)) * 512 +
                    ((((nt * 2) + (lr >> 3)) & 3) * 16 + lg * 4) * 8 + (lr & 7);
#pragma unroll
        for (int rg = 0; rg < 4; ++rg)
          sP[hl][cbase + rg * 8] = (_Float16)p2[rs][nt][rg];
      }
    }
    __syncthreads();

    f32x4 oacc[2][4];
#pragma unroll
    for (int ds = 0; ds < 2; ++ds)
#pragma unroll
      for (int ntq = 0; ntq < 4; ++ntq) oacc[ds][ntq] = zero4;
#pragma unroll
    for (int tkt = 0; tkt < 2; ++tkt) {
      f16x8 bfp[4];
#pragma unroll
      for (int ntq = 0; ntq < 4; ++ntq)
        bfp[ntq] = *(const f16x8*)&sP[hl][(ntq * 2 + tkt) * 512 + lane * 8];
#pragma unroll
      for (int ds = 0; ds < 2; ++ds)
#pragma unroll
        for (int ntq = 0; ntq < 4; ++ntq)
          oacc[ds][ntq] = MFMA16(afv[ds][tkt], bfp[ntq], oacc[ds][ntq]);
    }

#pragma unroll
    for (int ds = 0; ds < 2; ++ds) {
      const int dsg = part * 2 + ds;
      const int e0 = (lg & 1) * 4;
      const int lgt = (dsg * 2 + (lg >> 1)) & 3;
#pragma unroll
      for (int ntq = 0; ntq < 4; ++ntq) {
        size_t pos = ((size_t)(w * 4 + ntq) * 16 + h * 2 + (dsg >> 1)) * 512 +
                     (lgt * 16 + lr) * 8 + e0;
        f16x4 hv;
        hv[0] = (_Float16)oacc[ds][ntq][0]; hv[1] = (_Float16)oacc[ds][ntq][1];
        hv[2] = (_Float16)oacc[ds][ntq][2]; hv[3] = (_Float16)oacc[ds][ntq][3];
        *(f16x4*)(hP + pos) = hv;
      }
    }
    __syncthreads();
  }
}

// ---------------------------------------------------------------------------
// Fallback (verified R2 kernel) for small workspaces: fused, 128 KB LDS.
// ---------------------------------------------------------------------------
__global__ __launch_bounds__(512, 2) void attn_fused(
    const float* __restrict__ x, const _Float16* __restrict__ wqkvP,
    const _Float16* __restrict__ wprojP, const float* __restrict__ bproj,
    float* __restrict__ out) {
  __shared__ __align__(16) _Float16 sX[64 * 512];
  __shared__ __align__(16) _Float16 sHeads[4][2][4096];

  const int tid = threadIdx.x;
  const int wid = tid >> 6;
  const int lane = tid & 63;
  const int lg = lane >> 4;
  const int lr = lane & 15;

  _Float16* sQ0 = &sHeads[0][0][0];
  _Float16* sK0 = &sHeads[1][0][0];
  _Float16* sVT0 = &sHeads[2][0][0];
  _Float16* sPO0 = &sHeads[3][0][0];

  const float4* xv = (const float4*)(x + (size_t)blockIdx.x * 32768);
#pragma unroll
  for (int it = 0; it < 8; ++it) {
    int g = tid + it * 512;
    int r = g >> 6, c0 = (g & 63) << 3;
    float4 a = xv[(r << 7) + (c0 >> 2)];
    float4 b = xv[(r << 7) + (c0 >> 2) + 1];
    f16x8 hv;
    hv[0] = (_Float16)a.x; hv[1] = (_Float16)a.y;
    hv[2] = (_Float16)a.z; hv[3] = (_Float16)a.w;
    hv[4] = (_Float16)b.x; hv[5] = (_Float16)b.y;
    hv[6] = (_Float16)b.z; hv[7] = (_Float16)b.w;
    *(f16x8*)&sX[swz512(r, c0)] = hv;
  }
  const f32x4 zero4 = {0.f, 0.f, 0.f, 0.f};
  f32x4 accO[4][4];
#pragma unroll
  for (int i = 0; i < 4; ++i)
#pragma unroll
    for (int j = 0; j < 4; ++j) accO[i][j] = zero4;
  __syncthreads();

  for (int hp = 0; hp < 4; ++hp) {
    int hu[3], su[3], stu[3];
    const _Float16* bp[3];
    f32x4 acc[3][4];
#pragma unroll
    for (int i = 0; i < 3; ++i) {
      int u = wid + 8 * i;
      int hh = u & 1, v2 = u >> 1;
      int sec = v2 % 3, strip = v2 / 3;
      hu[i] = hh; su[i] = sec; stu[i] = strip;
      int r16 = sec * 32 + (hp * 2 + hh) * 4 + strip;
      bp[i] = wqkvP + (size_t)r16 * 8192 + lane * 8;
#pragma unroll
      for (int rt = 0; rt < 4; ++rt) acc[i][rt] = zero4;
    }
    f16x8 bf[3][3];
#pragma unroll
    for (int d = 0; d < 3; ++d)
#pragma unroll
      for (int i = 0; i < 3; ++i) bf[d][i] = *(const f16x8*)(bp[i] + d * 512);
    f16x8 af[2][4];
#pragma unroll
    for (int rt = 0; rt < 4; ++rt)
      af[0][rt] = *(const f16x8*)&sX[swz512(rt * 16 + lr, lg * 8)];
#pragma unroll
    for (int ks = 0; ks < 16; ++ks) {
      if (ks < 15) {
#pragma unroll
        for (int rt = 0; rt < 4; ++rt)
          af[(ks + 1) & 1][rt] =
              *(const f16x8*)&sX[swz512(rt * 16 + lr, (ks + 1) * 32 + lg * 8)];
      }
#pragma unroll
      for (int i = 0; i < 3; ++i)
#pragma unroll
        for (int rt = 0; rt < 4; ++rt)
          acc[i][rt] = MFMA16(af[ks & 1][rt], bf[ks % 3][i], acc[i][rt]);
      if (ks + 3 < 16) {
#pragma unroll
        for (int i = 0; i < 3; ++i)
          bf[ks % 3][i] = *(const f16x8*)(bp[i] + (ks + 3) * 512);
      }
    }
#pragma unroll
    for (int i = 0; i < 3; ++i) {
      int hh = hu[i], sec = su[i], strip = stu[i];
      _Float16* dq = sQ0 + hh * 4096;
      _Float16* dk = sK0 + hh * 4096;
      _Float16* dv = sVT0 + hh * 4096;
#pragma unroll
      for (int rt = 0; rt < 4; ++rt)
#pragma unroll
        for (int rg = 0; rg < 4; ++rg) {
          int row = rt * 16 + lg * 4 + rg;
          int col = strip * 16 + lr;
          _Float16 v = (_Float16)acc[i][rt][rg];
          if (sec == 0) dq[swz64(row, col)] = v;
          else if (sec == 1) dk[swz64(row, col)] = v;
          else dv[swz64(col, row)] = v;
        }
    }
    __syncthreads();
    {
      const int hh = wid >> 2;
      const int rs = wid & 3;
      const _Float16* mQ = sQ0 + hh * 4096;
      const _Float16* mK = sK0 + hh * 4096;
      const _Float16* mV = sVT0 + hh * 4096;
      _Float16* mP = sPO0 + hh * 4096;
      f32x4 sacc[4];
#pragma unroll
      for (int nt = 0; nt < 4; ++nt) sacc[nt] = zero4;
#pragma unroll
      for (int ks = 0; ks < 2; ++ks) {
        f16x8 afq = *(const f16x8*)&mQ[swz64(rs * 16 + lr, ks * 32 + lg * 8)];
#pragma unroll
        for (int nt = 0; nt < 4; ++nt) {
          f16x8 bfk = *(const f16x8*)&mK[swz64(nt * 16 + lr, ks * 32 + lg * 8)];
          sacc[nt] = MFMA16(afq, bfk, sacc[nt]);
        }
      }
      float p2[4][4];
#pragma unroll
      for (int rg = 0; rg < 4; ++rg) {
        int row = rs * 16 + lg * 4 + rg;
        float m = -1e30f;
#pragma unroll
        for (int nt = 0; nt < 4; ++nt) {
          int col = nt * 16 + lr;
          float v = (col <= row) ? sacc[nt][rg] : -1e30f;
          m = fmaxf(m, v);
        }
#pragma unroll
        for (int off = 8; off >= 1; off >>= 1) m = fmaxf(m, __shfl_xor(m, off));
        float e[4], s1 = 0.f;
#pragma unroll
        for (int nt = 0; nt < 4; ++nt) {
          int col = nt * 16 + lr;
          e[nt] = (col <= row) ? __expf(sacc[nt][rg] - m) : 0.f;
          s1 += e[nt];
        }
#pragma unroll
        for (int off = 8; off >= 1; off >>= 1) s1 += __shfl_xor(s1, off);
        float inv1 = 1.f / s1;
        float e2[4], s2 = 0.f;
#pragma unroll
        for (int nt = 0; nt < 4; ++nt) {
          e2[nt] = __expf(e[nt] * inv1);
          s2 += e2[nt];
        }
#pragma unroll
        for (int off = 8; off >= 1; off >>= 1) s2 += __shfl_xor(s2, off);
        float inv2 = 1.f / s2;
#pragma unroll
        for (int nt = 0; nt < 4; ++nt) p2[nt][rg] = e2[nt] * inv2;
      }
#pragma unroll
      for (int nt = 0; nt < 4; ++nt)
#pragma unroll
        for (int rg = 0; rg < 4; ++rg)
          mP[swz64(rs * 16 + lg * 4 + rg, nt * 16 + lr)] = (_Float16)p2[nt][rg];
      asm volatile("" ::: "memory");
      f32x4 oacc[4];
#pragma unroll
      for (int nt = 0; nt < 4; ++nt) oacc[nt] = zero4;
#pragma unroll
      for (int ks = 0; ks < 2; ++ks) {
        f16x8 afp = *(const f16x8*)&mP[swz64(rs * 16 + lr, ks * 32 + lg * 8)];
#pragma unroll
        for (int nt = 0; nt < 4; ++nt) {
          f16x8 bfv = *(const f16x8*)&mV[swz64(nt * 16 + lr, ks * 32 + lg * 8)];
          oacc[nt] = MFMA16(afp, bfv, oacc[nt]);
        }
      }
      asm volatile("" ::: "memory");
#pragma unroll
      for (int nt = 0; nt < 4; ++nt)
#pragma unroll
        for (int rg = 0; rg < 4; ++rg)
          mP[swz64(rs * 16 + lg * 4 + rg, nt * 16 + lr)] = (_Float16)oacc[nt][rg];
    }
    __syncthreads();
    {
      f16x8 bfC[2][4], afC[2][4];
#pragma unroll
      for (int rt = 0; rt < 4; ++rt)
        afC[0][rt] = *(const f16x8*)&sPO0[swz64(rt * 16 + lr, lg * 8)];
#pragma unroll
      for (int nt = 0; nt < 4; ++nt)
        bfC[0][nt] = *(const f16x8*)(wprojP + (size_t)(wid * 4 + nt) * 8192 +
                                     (size_t)(hp * 4) * 512 + lane * 8);
#pragma unroll
      for (int g = 0; g < 4; ++g) {
        if (g < 3) {
          int hn = (g + 1) >> 1, kn = (g + 1) & 1;
#pragma unroll
          for (int rt = 0; rt < 4; ++rt)
            afC[(g + 1) & 1][rt] = *(const f16x8*)&sPO0[hn * 4096 +
                swz64(rt * 16 + lr, kn * 32 + lg * 8)];
#pragma unroll
          for (int nt = 0; nt < 4; ++nt)
            bfC[(g + 1) & 1][nt] =
                *(const f16x8*)(wprojP + (size_t)(wid * 4 + nt) * 8192 +
                                (size_t)(hp * 4 + g + 1) * 512 + lane * 8);
        }
#pragma unroll
        for (int nt = 0; nt < 4; ++nt)
#pragma unroll
          for (int rt = 0; rt < 4; ++rt)
            accO[rt][nt] = MFMA16(afC[g & 1][rt], bfC[g & 1][nt], accO[rt][nt]);
      }
    }
  }
  __syncthreads();
  float bias_r[4];
#pragma unroll
  for (int nt = 0; nt < 4; ++nt) bias_r[nt] = bproj[wid * 64 + nt * 16 + lr];
  float* sEp = (float*)&sHeads[0][0][0];
  size_t base = (size_t)blockIdx.x * 32768;
#pragma unroll
  for (int half = 0; half < 2; ++half) {
#pragma unroll
    for (int rr = 0; rr < 2; ++rr) {
      int rt = half * 2 + rr;
#pragma unroll
      for (int nt = 0; nt < 4; ++nt)
#pragma unroll
        for (int rg = 0; rg < 4; ++rg) {
          int r = rr * 16 + lg * 4 + rg;
          int c = wid * 64 + nt * 16 + lr;
          sEp[r * 512 + (c ^ (((r >> 2) & 1) << 4))] = accO[rt][nt][rg] + bias_r[nt];
        }
    }
    __syncthreads();
#pragma unroll
    for (int j = 0; j < 8; ++j) {
      int f4 = tid + j * 512;
      int r = f4 >> 7;
      int c0 = (f4 & 127) << 2;
      float4 v = *(const float4*)&sEp[r * 512 + (c0 ^ (((r >> 2) & 1) << 4))];
      *(float4*)&out[base + (size_t)(half * 32 + r) * 512 + c0] = v;
    }
    if (half == 0) __syncthreads();
  }
}

extern "C" void kernel_launch(void* const* d_in, const int* in_sizes, int n_in,
                              void* d_out, int out_size, void* d_ws, size_t ws_size,
                              hipStream_t stream) {
  const float* x = (const float*)d_in[0];
  const float* Wqkv = (const float*)d_in[1];
  const float* Wproj = (const float*)d_in[2];
  const float* bproj = (const float*)d_in[3];
  float* out = (float*)d_out;

  const size_t W1 = 786432, W2 = 262144, XN = 33554432;
  const size_t QN = 100663296, HN = 33554432;
  _Float16* wqkvP = (_Float16*)d_ws;
  _Float16* wprojP = wqkvP + W1;
  _Float16* xP = wprojP + W2;
  _Float16* qkvP = xP + XN;
  _Float16* hP = qkvP + QN;
  const size_t NEED = (W1 + W2 + XN + QN + HN) * 2;

  prep_weights<<<dim3(4096), dim3(256), 0, stream>>>(Wqkv, Wproj, wqkvP, wprojP);
  if (ws_size >= NEED) {
    prep_x<<<dim3(1024), dim3(512), 0, stream>>>(x, xP);
    // QKV: A = Wqkv^T rows (12 x 128-tiles), B = xP tokens (512 tiles)
    gemm128<0><<<dim3(6144), dim3(256), 0, stream>>>(wqkvP, xP, qkvP, nullptr,
                                                     nullptr, 12);
    attn_win<<<dim3(1024), dim3(512), 0, stream>>>(qkvP, hP);
    // proj: A = Wproj^T rows (4 tiles), B = hP tokens (512 tiles)
    gemm128<2><<<dim3(2048), dim3(256), 0, stream>>>(wprojP, hP, nullptr, out,
                                                     bproj, 4);
  } else {
    attn_fused<<<dim3(1024), dim3(512), 0, stream>>>(x, wqkvP, wprojP, bproj, out);
  }
}

// Round 16
// 289.164 us; speedup vs baseline: 1.0415x; 1.0192x over previous
//
#include <hip/hip_runtime.h>

// x[16,4096,512] fp32 -> windows [1024, 64, 512]
//   qkv = xw @ Wqkv[512,1536]; per head (8 x 64d): S = QK^T/8, causal mask,
//   softmax, softmax AGAIN (no re-mask), out = P2 @ V; concat; @ Wproj + bproj.
//
// R16 pipeline (4 dispatches):
//   prep_all (weights + x packed, one grid) -> gemm2p<0> (Q/K) ->
//   gemm2p<1> (V) -> attn_win -> gemm2p<2> (proj)
//
// FP(R) packing of M[r][k], k in [0,512):
//   pos(r,k) = ((r>>4)*16 + (k>>5))*512 + (((k>>3)&3)*16 + (r&15))*8 + (k&7)
//
// Session findings (R6-R15): six K-loop schedules + both tile shapes all land
// at 33-38% MfmaUtil / 830-900 TF = the documented plain-HIP 2-barrier
// structural plateau (m97/m98). attn_win and prep_x are near HBM floors.
// R16 removes the last launch gap by merging the two prep dispatches.

typedef _Float16 f16x8 __attribute__((ext_vector_type(8)));
typedef _Float16 f16x4 __attribute__((ext_vector_type(4)));
typedef float f32x4 __attribute__((ext_vector_type(4)));

#define MFMA16(a, b, c) __builtin_amdgcn_mfma_f32_16x16x32_f16((a), (b), (c), 0, 0, 0)

__device__ __forceinline__ int swz512(int r, int c) { return r * 512 + (c ^ ((r & 7) << 3)); }
__device__ __forceinline__ int swz64(int r, int c) { return r * 64 + (c ^ ((r & 7) << 3)); }

typedef const __attribute__((address_space(1))) void* gas1_t;
typedef __attribute__((address_space(3))) void* las3_t;

__device__ __forceinline__ void stage16(const _Float16* g, _Float16* lbase, int lane) {
#if __has_builtin(__builtin_amdgcn_global_load_lds)
  __builtin_amdgcn_global_load_lds((gas1_t)(const void*)g, (las3_t)(void*)lbase, 16, 0, 0);
#else
  *(f16x8*)(lbase + lane * 8) = *(const f16x8*)g;
#endif
}

// ---------------------------------------------------------------------------
// prep_all: one grid. Blocks [0,1024): pack x window -> xP (when doX).
// Blocks [1024,3072): pack weights (wqkvP scaled-Q / wprojP), 512 thr each.
// Weight blocks run in the shadow of the HBM-bound x staging.
// ---------------------------------------------------------------------------
__global__ __launch_bounds__(512) void prep_all(
    const float* __restrict__ x, const float* __restrict__ Wqkv,
    const float* __restrict__ Wproj, _Float16* __restrict__ xP,
    _Float16* __restrict__ wqkvP, _Float16* __restrict__ wprojP, int doX) {
  __shared__ __align__(16) _Float16 sX[64 * 512];
  const int tid = threadIdx.x;
  const int bid = blockIdx.x;
  if (bid >= 1024) {
    int idx = (bid - 1024) * 512 + tid;  // [0, 1048576)
    if (idx < 786432) {
      int r16 = idx >> 13;
      int rem = idx & 8191;
      int kt = rem >> 9;
      int lane = (rem >> 3) & 63;
      int e = rem & 7;
      int row = r16 * 16 + (lane & 15);
      int k = kt * 32 + (lane >> 4) * 8 + e;
      float v = Wqkv[k * 1536 + row];
      if (row < 512) v *= 0.125f;  // fold hd^-0.5 into Q
      wqkvP[idx] = (_Float16)v;
    } else {
      int j = idx - 786432;
      int r16 = j >> 13;
      int rem = j & 8191;
      int kt = rem >> 9;
      int lane = (rem >> 3) & 63;
      int e = rem & 7;
      int n = r16 * 16 + (lane & 15);
      int k = kt * 32 + (lane >> 4) * 8 + e;
      wprojP[j] = (_Float16)Wproj[k * 512 + n];
    }
    return;
  }
  if (!doX) return;
  const float4* xv = (const float4*)(x + (size_t)bid * 32768);
#pragma unroll
  for (int it = 0; it < 8; ++it) {
    int g = tid + it * 512;
    int r = g >> 6, c0 = (g & 63) << 3;
    float4 a = xv[(r << 7) + (c0 >> 2)];
    float4 b = xv[(r << 7) + (c0 >> 2) + 1];
    f16x8 hv;
    hv[0] = (_Float16)a.x; hv[1] = (_Float16)a.y;
    hv[2] = (_Float16)a.z; hv[3] = (_Float16)a.w;
    hv[4] = (_Float16)b.x; hv[5] = (_Float16)b.y;
    hv[6] = (_Float16)b.z; hv[7] = (_Float16)b.w;
    *(f16x8*)&sX[swz512(r, c0)] = hv;
  }
  __syncthreads();
  _Float16* dst = xP + (size_t)bid * 32768;
#pragma unroll
  for (int it = 0; it < 8; ++it) {
    int c8 = tid + it * 512;
    int rt = c8 >> 10, ks = (c8 >> 6) & 15, ln = c8 & 63;
    int row = rt * 16 + (ln & 15);
    int k0 = ks * 32 + (ln >> 4) * 8;
    f16x8 v = *(const f16x8*)&sX[swz512(row, k0)];
    *(f16x8*)(dst + c8 * 8) = v;
  }
}

// ---------------------------------------------------------------------------
// gemm2p: D[i][j] = sum_k A[i,k] B[j,k]. 256x256 tile, BK=32, K=512 (16 steps).
// 8 waves (512 thr); wave owns 128x64 (acc 8x4). LDS 64KB (2 slots).
// (verified R9: bare counted vmcnt, 2 barriers/K-tile)
// MODE 0: A=Wqkv^T Q/K rows, B=xP tokens -> scatter Q/K to qkvP
// MODE 1: A=xP tokens, B=V weight rows  -> scatter V^T to qkvP
// MODE 2: A=Wproj^T rows, B=hP tokens   -> out fp32 + bias
// ---------------------------------------------------------------------------
template <int MODE>
__global__ __launch_bounds__(512, 2) void gemm2p(
    const _Float16* __restrict__ Afp, const _Float16* __restrict__ Bfp,
    _Float16* __restrict__ dst16, float* __restrict__ out,
    const float* __restrict__ bproj, int rTiles) {
  __shared__ __align__(16) _Float16 sG[2][2][16][512];  // 64KB
  const int tid = threadIdx.x;
  const int wid = tid >> 6;
  const int lane = tid & 63;
  const int lg = lane >> 4, lr = lane & 15;
  const int wr = wid >> 2, wc = wid & 3;
  const int wr8 = wr * 8, wc4 = wc * 4, lane8 = lane * 8;
  const int cs = wid * 2;

  // XCD-chunked bijective swizzle (nwg % 8 == 0 for all modes)
  const int nwg = gridDim.x;
  const int bid = blockIdx.x;
  const int swz = (bid & 7) * (nwg >> 3) + (bid >> 3);
  const int r0 = (swz % rTiles) * 256, c0 = (swz / rTiles) * 256;

  const _Float16* Abase = Afp + (size_t)(r0 >> 4) * 8192 + lane8;
  const _Float16* Bbase = Bfp + (size_t)(c0 >> 4) * 8192 + lane8;

  auto STAGE = [&](int s, int T) {
    stage16(Abase + (size_t)cs * 8192 + T * 512, &sG[s][0][cs][0], lane);
    stage16(Abase + (size_t)(cs + 1) * 8192 + T * 512, &sG[s][0][cs + 1][0], lane);
    stage16(Bbase + (size_t)cs * 8192 + T * 512, &sG[s][1][cs][0], lane);
    stage16(Bbase + (size_t)(cs + 1) * 8192 + T * 512, &sG[s][1][cs + 1][0], lane);
  };

  const f32x4 zero4 = {0.f, 0.f, 0.f, 0.f};
  f32x4 acc[8][4];
#pragma unroll
  for (int i = 0; i < 8; ++i)
#pragma unroll
    for (int j = 0; j < 4; ++j) acc[i][j] = zero4;

  STAGE(0, 0);
  int cur = 0;
  for (int t = 0; t < 16; ++t) {
    const int Tn = (t + 1 < 16) ? t + 1 : 15;  // tail re-stage: harmless
    STAGE(cur ^ 1, Tn);
    asm volatile("s_waitcnt vmcnt(4)");  // drain tile t; t+1 stays in flight
    __builtin_amdgcn_s_barrier();
    __builtin_amdgcn_sched_barrier(0);
    f16x8 a[8], b[4];
#pragma unroll
    for (int mi = 0; mi < 8; ++mi)
      a[mi] = *(const f16x8*)&sG[cur][0][wr8 + mi][lane8];
#pragma unroll
    for (int ni = 0; ni < 4; ++ni)
      b[ni] = *(const f16x8*)&sG[cur][1][wc4 + ni][lane8];
    __builtin_amdgcn_s_setprio(1);
#pragma unroll
    for (int mi = 0; mi < 8; ++mi)
#pragma unroll
      for (int ni = 0; ni < 4; ++ni)
        acc[mi][ni] = MFMA16(a[mi], b[ni], acc[mi][ni]);
    __builtin_amdgcn_s_setprio(0);
    asm volatile("s_waitcnt lgkmcnt(0)");
    __builtin_amdgcn_sched_barrier(0);
    __builtin_amdgcn_s_barrier();
    __builtin_amdgcn_sched_barrier(0);
    cur ^= 1;
  }

  // ============================ epilogue =================================
  if constexpr (MODE == 0) {
#pragma unroll
    for (int mi = 0; mi < 8; ++mi) {
      int nb = r0 + wr * 128 + mi * 16 + lg * 4;
      int sec = nb >> 9, h = (nb >> 6) & 7, db = nb & 63;
      int coff = (db >> 5) * 512 + (((db >> 3) & 3) * 16) * 8 + (db & 7);
#pragma unroll
      for (int ni = 0; ni < 4; ++ni) {
        int tg = c0 + wc * 64 + ni * 16 + lr;
        int w = tg >> 6, t = tg & 63;
        size_t pos = ((size_t)w * 24 + sec * 8 + h) * 4096 +
                     (size_t)((t >> 4) * 2) * 512 + coff + (t & 15) * 8;
        f16x4 hv;
        hv[0] = (_Float16)acc[mi][ni][0]; hv[1] = (_Float16)acc[mi][ni][1];
        hv[2] = (_Float16)acc[mi][ni][2]; hv[3] = (_Float16)acc[mi][ni][3];
        *(f16x4*)(dst16 + pos) = hv;
      }
    }
  } else if constexpr (MODE == 1) {
#pragma unroll
    for (int mi = 0; mi < 8; ++mi) {
      int tbg = r0 + wr * 128 + mi * 16 + lg * 4;
      int w = tbg >> 6, tb = tbg & 63;
      int coff = (tb >> 5) * 512 + (((tb >> 3) & 3) * 16) * 8 + (tb & 7);
#pragma unroll
      for (int ni = 0; ni < 4; ++ni) {
        int cv = c0 + wc * 64 + ni * 16 + lr;
        int h = cv >> 6, d = cv & 63;
        size_t pos = ((size_t)w * 24 + 16 + h) * 4096 +
                     (size_t)((d >> 4) * 2) * 512 + coff + (d & 15) * 8;
        f16x4 hv;
        hv[0] = (_Float16)acc[mi][ni][0]; hv[1] = (_Float16)acc[mi][ni][1];
        hv[2] = (_Float16)acc[mi][ni][2]; hv[3] = (_Float16)acc[mi][ni][3];
        *(f16x4*)(dst16 + pos) = hv;
      }
    }
  } else {
#pragma unroll
    for (int mi = 0; mi < 8; ++mi) {
      int nb = r0 + wr * 128 + mi * 16 + lg * 4;
      float4 bi = *(const float4*)&bproj[nb];
#pragma unroll
      for (int ni = 0; ni < 4; ++ni) {
        int tg = c0 + wc * 64 + ni * 16 + lr;
        float4 v;
        v.x = acc[mi][ni][0] + bi.x; v.y = acc[mi][ni][1] + bi.y;
        v.z = acc[mi][ni][2] + bi.z; v.w = acc[mi][ni][3] + bi.w;
        *(float4*)&out[(size_t)tg * 512 + nb] = v;
      }
    }
  }
}

// ---------------------------------------------------------------------------
// attn_win: 1 block = 1 window, 512 thr. 2 rounds x 4 heads; wave=(head,part).
// (verified R5)
// ---------------------------------------------------------------------------
__global__ __launch_bounds__(512, 4) void attn_win(
    const _Float16* __restrict__ qkvP, _Float16* __restrict__ hP) {
  __shared__ __align__(16) _Float16 sP[4][4096];
  const int tid = threadIdx.x;
  const int wid = tid >> 6;
  const int lane = tid & 63;
  const int lg = lane >> 4, lr = lane & 15;
  const int hl = wid >> 1, part = wid & 1;
  const int w = blockIdx.x;
  const f32x4 zero4 = {0.f, 0.f, 0.f, 0.f};

  for (int hr = 0; hr < 2; ++hr) {
    const int h = hr * 4 + hl;
    const _Float16* Qb = qkvP + ((size_t)w * 24 + h) * 4096 + lane * 8;
    const _Float16* Kb = qkvP + ((size_t)w * 24 + 8 + h) * 4096 + lane * 8;
    const _Float16* Vb = qkvP + ((size_t)w * 24 + 16 + h) * 4096 + lane * 8;

    f16x8 afq[2][2], bfk[4][2];
#pragma unroll
    for (int rs = 0; rs < 2; ++rs)
#pragma unroll
      for (int dkt = 0; dkt < 2; ++dkt)
        afq[rs][dkt] = *(const f16x8*)(Qb + ((part * 2 + rs) * 2 + dkt) * 512);
#pragma unroll
    for (int nt = 0; nt < 4; ++nt)
#pragma unroll
      for (int dkt = 0; dkt < 2; ++dkt)
        bfk[nt][dkt] = *(const f16x8*)(Kb + (nt * 2 + dkt) * 512);
    f32x4 sacc[2][4];
#pragma unroll
    for (int rs = 0; rs < 2; ++rs)
#pragma unroll
      for (int nt = 0; nt < 4; ++nt) sacc[rs][nt] = zero4;
#pragma unroll
    for (int dkt = 0; dkt < 2; ++dkt)
#pragma unroll
      for (int rs = 0; rs < 2; ++rs)
#pragma unroll
        for (int nt = 0; nt < 4; ++nt)
          sacc[rs][nt] = MFMA16(afq[rs][dkt], bfk[nt][dkt], sacc[rs][nt]);

    f16x8 afv[2][2];
#pragma unroll
    for (int ds = 0; ds < 2; ++ds)
#pragma unroll
      for (int tkt = 0; tkt < 2; ++tkt)
        afv[ds][tkt] = *(const f16x8*)(Vb + ((part * 2 + ds) * 2 + tkt) * 512);

    float p2[2][4][4];
#pragma unroll
    for (int rs = 0; rs < 2; ++rs) {
      const int rsg = part * 2 + rs;
#pragma unroll
      for (int rg = 0; rg < 4; ++rg) {
        int row = rsg * 16 + lg * 4 + rg;
        float m = -1e30f;
#pragma unroll
        for (int nt = 0; nt < 4; ++nt) {
          int col = nt * 16 + lr;
          float v = (col <= row) ? sacc[rs][nt][rg] : -1e30f;
          m = fmaxf(m, v);
        }
#pragma unroll
        for (int off = 8; off >= 1; off >>= 1) m = fmaxf(m, __shfl_xor(m, off));
        float e[4], s1 = 0.f;
#pragma unroll
        for (int nt = 0; nt < 4; ++nt) {
          int col = nt * 16 + lr;
          e[nt] = (col <= row) ? __expf(sacc[rs][nt][rg] - m) : 0.f;
          s1 += e[nt];
        }
#pragma unroll
        for (int off = 8; off >= 1; off >>= 1) s1 += __shfl_xor(s1, off);
        float inv1 = 1.f / s1;
        float e2[4], s2 = 0.f;
#pragma unroll
        for (int nt = 0; nt < 4; ++nt) {
          e2[nt] = __expf(e[nt] * inv1);
          s2 += e2[nt];
        }
#pragma unroll
        for (int off = 8; off >= 1; off >>= 1) s2 += __shfl_xor(s2, off);
        float inv2 = 1.f / s2;
#pragma unroll
        for (int nt = 0; nt < 4; ++nt) p2[rs][nt][rg] = e2[nt] * inv2;
      }
    }

#pragma unroll
    for (int rs = 0; rs < 2; ++rs) {
      const int rsg = part * 2 + rs;
#pragma unroll
      for (int nt = 0; nt < 4; ++nt) {
        int cbase = (rsg * 2 + (nt >> 1)) * 512 +
                    ((((nt * 2) + (lr >> 3)) & 3) * 16 + lg * 4) * 8 + (lr & 7);
#pragma unroll
        for (int rg = 0; rg < 4; ++rg)
          sP[hl][cbase + rg * 8] = (_Float16)p2[rs][nt][rg];
      }
    }
    __syncthreads();

    f32x4 oacc[2][4];
#pragma unroll
    for (int ds = 0; ds < 2; ++ds)
#pragma unroll
      for (int ntq = 0; ntq < 4; ++ntq) oacc[ds][ntq] = zero4;
#pragma unroll
    for (int tkt = 0; tkt < 2; ++tkt) {
      f16x8 bfp[4];
#pragma unroll
      for (int ntq = 0; ntq < 4; ++ntq)
        bfp[ntq] = *(const f16x8*)&sP[hl][(ntq * 2 + tkt) * 512 + lane * 8];
#pragma unroll
      for (int ds = 0; ds < 2; ++ds)
#pragma unroll
        for (int ntq = 0; ntq < 4; ++ntq)
          oacc[ds][ntq] = MFMA16(afv[ds][tkt], bfp[ntq], oacc[ds][ntq]);
    }

#pragma unroll
    for (int ds = 0; ds < 2; ++ds) {
      const int dsg = part * 2 + ds;
      const int e0 = (lg & 1) * 4;
      const int lgt = (dsg * 2 + (lg >> 1)) & 3;
#pragma unroll
      for (int ntq = 0; ntq < 4; ++ntq) {
        size_t pos = ((size_t)(w * 4 + ntq) * 16 + h * 2 + (dsg >> 1)) * 512 +
                     (lgt * 16 + lr) * 8 + e0;
        f16x4 hv;
        hv[0] = (_Float16)oacc[ds][ntq][0]; hv[1] = (_Float16)oacc[ds][ntq][1];
        hv[2] = (_Float16)oacc[ds][ntq][2]; hv[3] = (_Float16)oacc[ds][ntq][3];
        *(f16x4*)(hP + pos) = hv;
      }
    }
    __syncthreads();
  }
}

// ---------------------------------------------------------------------------
// Fallback (verified R2 kernel) for small workspaces: fused, 128 KB LDS.
// ---------------------------------------------------------------------------
__global__ __launch_bounds__(512, 2) void attn_fused(
    const float* __restrict__ x, const _Float16* __restrict__ wqkvP,
    const _Float16* __restrict__ wprojP, const float* __restrict__ bproj,
    float* __restrict__ out) {
  __shared__ __align__(16) _Float16 sX[64 * 512];
  __shared__ __align__(16) _Float16 sHeads[4][2][4096];

  const int tid = threadIdx.x;
  const int wid = tid >> 6;
  const int lane = tid & 63;
  const int lg = lane >> 4;
  const int lr = lane & 15;

  _Float16* sQ0 = &sHeads[0][0][0];
  _Float16* sK0 = &sHeads[1][0][0];
  _Float16* sVT0 = &sHeads[2][0][0];
  _Float16* sPO0 = &sHeads[3][0][0];

  const float4* xv = (const float4*)(x + (size_t)blockIdx.x * 32768);
#pragma unroll
  for (int it = 0; it < 8; ++it) {
    int g = tid + it * 512;
    int r = g >> 6, c0 = (g & 63) << 3;
    float4 a = xv[(r << 7) + (c0 >> 2)];
    float4 b = xv[(r << 7) + (c0 >> 2) + 1];
    f16x8 hv;
    hv[0] = (_Float16)a.x; hv[1] = (_Float16)a.y;
    hv[2] = (_Float16)a.z; hv[3] = (_Float16)a.w;
    hv[4] = (_Float16)b.x; hv[5] = (_Float16)b.y;
    hv[6] = (_Float16)b.z; hv[7] = (_Float16)b.w;
    *(f16x8*)&sX[swz512(r, c0)] = hv;
  }
  const f32x4 zero4 = {0.f, 0.f, 0.f, 0.f};
  f32x4 accO[4][4];
#pragma unroll
  for (int i = 0; i < 4; ++i)
#pragma unroll
    for (int j = 0; j < 4; ++j) accO[i][j] = zero4;
  __syncthreads();

  for (int hp = 0; hp < 4; ++hp) {
    int hu[3], su[3], stu[3];
    const _Float16* bp[3];
    f32x4 acc[3][4];
#pragma unroll
    for (int i = 0; i < 3; ++i) {
      int u = wid + 8 * i;
      int hh = u & 1, v2 = u >> 1;
      int sec = v2 % 3, strip = v2 / 3;
      hu[i] = hh; su[i] = sec; stu[i] = strip;
      int r16 = sec * 32 + (hp * 2 + hh) * 4 + strip;
      bp[i] = wqkvP + (size_t)r16 * 8192 + lane * 8;
#pragma unroll
      for (int rt = 0; rt < 4; ++rt) acc[i][rt] = zero4;
    }
    f16x8 bf[3][3];
#pragma unroll
    for (int d = 0; d < 3; ++d)
#pragma unroll
      for (int i = 0; i < 3; ++i) bf[d][i] = *(const f16x8*)(bp[i] + d * 512);
    f16x8 af[2][4];
#pragma unroll
    for (int rt = 0; rt < 4; ++rt)
      af[0][rt] = *(const f16x8*)&sX[swz512(rt * 16 + lr, lg * 8)];
#pragma unroll
    for (int ks = 0; ks < 16; ++ks) {
      if (ks < 15) {
#pragma unroll
        for (int rt = 0; rt < 4; ++rt)
          af[(ks + 1) & 1][rt] =
              *(const f16x8*)&sX[swz512(rt * 16 + lr, (ks + 1) * 32 + lg * 8)];
      }
#pragma unroll
      for (int i = 0; i < 3; ++i)
#pragma unroll
        for (int rt = 0; rt < 4; ++rt)
          acc[i][rt] = MFMA16(af[ks & 1][rt], bf[ks % 3][i], acc[i][rt]);
      if (ks + 3 < 16) {
#pragma unroll
        for (int i = 0; i < 3; ++i)
          bf[ks % 3][i] = *(const f16x8*)(bp[i] + (ks + 3) * 512);
      }
    }
#pragma unroll
    for (int i = 0; i < 3; ++i) {
      int hh = hu[i], sec = su[i], strip = stu[i];
      _Float16* dq = sQ0 + hh * 4096;
      _Float16* dk = sK0 + hh * 4096;
      _Float16* dv = sVT0 + hh * 4096;
#pragma unroll
      for (int rt = 0; rt < 4; ++rt)
#pragma unroll
        for (int rg = 0; rg < 4; ++rg) {
          int row = rt * 16 + lg * 4 + rg;
          int col = strip * 16 + lr;
          _Float16 v = (_Float16)acc[i][rt][rg];
          if (sec == 0) dq[swz64(row, col)] = v;
          else if (sec == 1) dk[swz64(row, col)] = v;
          else dv[swz64(col, row)] = v;
        }
    }
    __syncthreads();
    {
      const int hh = wid >> 2;
      const int rs = wid & 3;
      const _Float16* mQ = sQ0 + hh * 4096;
      const _Float16* mK = sK0 + hh * 4096;
      const _Float16* mV = sVT0 + hh * 4096;
      _Float16* mP = sPO0 + hh * 4096;
      f32x4 sacc[4];
#pragma unroll
      for (int nt = 0; nt < 4; ++nt) sacc[nt] = zero4;
#pragma unroll
      for (int ks = 0; ks < 2; ++ks) {
        f16x8 afq = *(const f16x8*)&mQ[swz64(rs * 16 + lr, ks * 32 + lg * 8)];
#pragma unroll
        for (int nt = 0; nt < 4; ++nt) {
          f16x8 bfk = *(const f16x8*)&mK[swz64(nt * 16 + lr, ks * 32 + lg * 8)];
          sacc[nt] = MFMA16(afq, bfk, sacc[nt]);
        }
      }
      float p2[4][4];
#pragma unroll
      for (int rg = 0; rg < 4; ++rg) {
        int row = rs * 16 + lg * 4 + rg;
        float m = -1e30f;
#pragma unroll
        for (int nt = 0; nt < 4; ++nt) {
          int col = nt * 16 + lr;
          float v = (col <= row) ? sacc[nt][rg] : -1e30f;
          m = fmaxf(m, v);
        }
#pragma unroll
        for (int off = 8; off >= 1; off >>= 1) m = fmaxf(m, __shfl_xor(m, off));
        float e[4], s1 = 0.f;
#pragma unroll
        for (int nt = 0; nt < 4; ++nt) {
          int col = nt * 16 + lr;
          e[nt] = (col <= row) ? __expf(sacc[nt][rg] - m) : 0.f;
          s1 += e[nt];
        }
#pragma unroll
        for (int off = 8; off >= 1; off >>= 1) s1 += __shfl_xor(s1, off);
        float inv1 = 1.f / s1;
        float e2[4], s2 = 0.f;
#pragma unroll
        for (int nt = 0; nt < 4; ++nt) {
          e2[nt] = __expf(e[nt] * inv1);
          s2 += e2[nt];
        }
#pragma unroll
        for (int off = 8; off >= 1; off >>= 1) s2 += __shfl_xor(s2, off);
        float inv2 = 1.f / s2;
#pragma unroll
        for (int nt = 0; nt < 4; ++nt) p2[nt][rg] = e2[nt] * inv2;
      }
#pragma unroll
      for (int nt = 0; nt < 4; ++nt)
#pragma unroll
        for (int rg = 0; rg < 4; ++rg)
          mP[swz64(rs * 16 + lg * 4 + rg, nt * 16 + lr)] = (_Float16)p2[nt][rg];
      asm volatile("" ::: "memory");
      f32x4 oacc[4];
#pragma unroll
      for (int nt = 0; nt < 4; ++nt) oacc[nt] = zero4;
#pragma unroll
      for (int ks = 0; ks < 2; ++ks) {
        f16x8 afp = *(const f16x8*)&mP[swz64(rs * 16 + lr, ks * 32 + lg * 8)];
#pragma unroll
        for (int nt = 0; nt < 4; ++nt) {
          f16x8 bfv = *(const f16x8*)&mV[swz64(nt * 16 + lr, ks * 32 + lg * 8)];
          oacc[nt] = MFMA16(afp, bfv, oacc[nt]);
        }
      }
      asm volatile("" ::: "memory");
#pragma unroll
      for (int nt = 0; nt < 4; ++nt)
#pragma unroll
        for (int rg = 0; rg < 4; ++rg)
          mP[swz64(rs * 16 + lg * 4 + rg, nt * 16 + lr)] = (_Float16)oacc[nt][rg];
    }
    __syncthreads();
    {
      f16x8 bfC[2][4], afC[2][4];
#pragma unroll
      for (int rt = 0; rt < 4; ++rt)
        afC[0][rt] = *(const f16x8*)&sPO0[swz64(rt * 16 + lr, lg * 8)];
#pragma unroll
      for (int nt = 0; nt < 4; ++nt)
        bfC[0][nt] = *(const f16x8*)(wprojP + (size_t)(wid * 4 + nt) * 8192 +
                                     (size_t)(hp * 4) * 512 + lane * 8);
#pragma unroll
      for (int g = 0; g < 4; ++g) {
        if (g < 3) {
          int hn = (g + 1) >> 1, kn = (g + 1) & 1;
#pragma unroll
          for (int rt = 0; rt < 4; ++rt)
            afC[(g + 1) & 1][rt] = *(const f16x8*)&sPO0[hn * 4096 +
                swz64(rt * 16 + lr, kn * 32 + lg * 8)];
#pragma unroll
          for (int nt = 0; nt < 4; ++nt)
            bfC[(g + 1) & 1][nt] =
                *(const f16x8*)(wprojP + (size_t)(wid * 4 + nt) * 8192 +
                                (size_t)(hp * 4 + g + 1) * 512 + lane * 8);
        }
#pragma unroll
        for (int nt = 0; nt < 4; ++nt)
#pragma unroll
          for (int rt = 0; rt < 4; ++rt)
            accO[rt][nt] = MFMA16(afC[g & 1][rt], bfC[g & 1][nt], accO[rt][nt]);
      }
    }
  }
  __syncthreads();
  float bias_r[4];
#pragma unroll
  for (int nt = 0; nt < 4; ++nt) bias_r[nt] = bproj[wid * 64 + nt * 16 + lr];
  float* sEp = (float*)&sHeads[0][0][0];
  size_t base = (size_t)blockIdx.x * 32768;
#pragma unroll
  for (int half = 0; half < 2; ++half) {
#pragma unroll
    for (int rr = 0; rr < 2; ++rr) {
      int rt = half * 2 + rr;
#pragma unroll
      for (int nt = 0; nt < 4; ++nt)
#pragma unroll
        for (int rg = 0; rg < 4; ++rg) {
          int r = rr * 16 + lg * 4 + rg;
          int c = wid * 64 + nt * 16 + lr;
          sEp[r * 512 + (c ^ (((r >> 2) & 1) << 4))] = accO[rt][nt][rg] + bias_r[nt];
        }
    }
    __syncthreads();
#pragma unroll
    for (int j = 0; j < 8; ++j) {
      int f4 = tid + j * 512;
      int r = f4 >> 7;
      int c0 = (f4 & 127) << 2;
      float4 v = *(const float4*)&sEp[r * 512 + (c0 ^ (((r >> 2) & 1) << 4))];
      *(float4*)&out[base + (size_t)(half * 32 + r) * 512 + c0] = v;
    }
    if (half == 0) __syncthreads();
  }
}

extern "C" void kernel_launch(void* const* d_in, const int* in_sizes, int n_in,
                              void* d_out, int out_size, void* d_ws, size_t ws_size,
                              hipStream_t stream) {
  const float* x = (const float*)d_in[0];
  const float* Wqkv = (const float*)d_in[1];
  const float* Wproj = (const float*)d_in[2];
  const float* bproj = (const float*)d_in[3];
  float* out = (float*)d_out;

  const size_t W1 = 786432, W2 = 262144, XN = 33554432;
  const size_t QN = 100663296, HN = 33554432;
  _Float16* wqkvP = (_Float16*)d_ws;
  _Float16* wprojP = wqkvP + W1;
  _Float16* xP = wprojP + W2;
  _Float16* qkvP = xP + XN;
  _Float16* hP = qkvP + QN;
  const size_t NEED = (W1 + W2 + XN + QN + HN) * 2;
  const int doX = (ws_size >= NEED) ? 1 : 0;

  prep_all<<<dim3(3072), dim3(512), 0, stream>>>(x, Wqkv, Wproj, xP, wqkvP,
                                                 wprojP, doX);
  if (doX) {
    // Q,K cols: A = Wqkv^T rows 0..1023 (4 row-tiles), B = xP tokens (256 tiles)
    gemm2p<0><<<dim3(1024), dim3(512), 0, stream>>>(wqkvP, xP, qkvP, nullptr, nullptr, 4);
    // V cols: A = xP tokens (256 tiles), B = V weight rows (2 tiles)
    gemm2p<1><<<dim3(512), dim3(512), 0, stream>>>(xP, wqkvP + (size_t)64 * 8192,
                                                   qkvP, nullptr, nullptr, 256);
    attn_win<<<dim3(1024), dim3(512), 0, stream>>>(qkvP, hP);
    // proj: A = Wproj^T rows (2 tiles), B = hP tokens (256 tiles)
    gemm2p<2><<<dim3(512), dim3(512), 0, stream>>>(wprojP, hP, nullptr, out, bproj, 2);
  } else {
    attn_fused<<<dim3(1024), dim3(512), 0, stream>>>(x, wqkvP, wprojP, bproj, out);
  }
}